// Round 1
// baseline (506.171 us; speedup 1.0000x reference)
//
#include <hip/hip_runtime.h>
#include <cstdint>
#include <cstddef>

// Problem constants
#define NB 1024        // batch of triples
#define NE 50000       // entities
#define NE_PAD 50048   // padded to 391*128
#define DCOL 512       // dimension D
#define ATTN_C 8       // cores

static const size_t SCORES_OFF = (size_t)NB * NE;        // 51,200,000
static const size_t F1_OFF = SCORES_OFF + 0;
static const size_t F2_OFF = SCORES_OFF + 1;
static const size_t F3_OFF = SCORES_OFF + 2;
static const size_t ATTN_OFF = SCORES_OFF + 3;

typedef float f32x4 __attribute__((ext_vector_type(4)));
typedef short s16x8 __attribute__((ext_vector_type(8)));

__device__ __forceinline__ unsigned short f2bf(float f) {
  union { float f; uint32_t u; } x; x.f = f;
  uint32_t u = x.u;
  uint32_t r = (u + 0x7fffu + ((u >> 16) & 1u)) >> 16;  // RNE
  return (unsigned short)r;
}

__device__ __forceinline__ void gload16(const void* g, void* l) {
  __builtin_amdgcn_global_load_lds(
      (const __attribute__((address_space(1))) uint32_t*)g,
      (__attribute__((address_space(3))) uint32_t*)l, 16, 0, 0);
}

// ---------------------------------------------------------------------------
// K1: gather h,r,t -> HR bf16 [NB][1024]; n1[b] = |h|^2+|r|^2+|t|^2
// ---------------------------------------------------------------------------
__global__ __launch_bounds__(256)
void gather_hr(const int* __restrict__ heads, const int* __restrict__ rels,
               const int* __restrict__ tails, const float* __restrict__ ew,
               const float* __restrict__ rw, unsigned short* __restrict__ hrb,
               float* __restrict__ n1) {
  int b = blockIdx.x, tid = threadIdx.x;
  const float* h = ew + (size_t)heads[b] * DCOL;
  const float* r = rw + (size_t)rels[b] * DCOL;
  const float* t = ew + (size_t)tails[b] * DCOL;
  float acc = 0.f;
  for (int d = tid; d < DCOL; d += 256) {
    float hv = h[d], rv = r[d], tv = t[d];
    hrb[(size_t)b * 1024 + d] = f2bf(hv);
    hrb[(size_t)b * 1024 + DCOL + d] = f2bf(rv);
    acc += hv * hv + rv * rv + tv * tv;
  }
  __shared__ float red[256];
  red[tid] = acc; __syncthreads();
  for (int s = 128; s > 0; s >>= 1) {
    if (tid < s) red[tid] += red[tid + s];
    __syncthreads();
  }
  if (tid == 0) n1[b] = red[0];
}

// ---------------------------------------------------------------------------
// K2: entity_w fp32 -> bf16, padded rows zeroed. Processes 4 elems/thread.
// ---------------------------------------------------------------------------
__global__ __launch_bounds__(256)
void cvt_pad(const float* __restrict__ src, unsigned short* __restrict__ dst,
             int n4valid, int n4tot) {
  int i = blockIdx.x * 256 + threadIdx.x;
  int stride = gridDim.x * 256;
  for (; i < n4tot; i += stride) {
    float x = 0.f, y = 0.f, z = 0.f, w = 0.f;
    if (i < n4valid) {
      float4 v = ((const float4*)src)[i];
      x = v.x; y = v.y; z = v.z; w = v.w;
    }
    union { unsigned short u[4]; uint2 v2; } o;
    o.u[0] = f2bf(x); o.u[1] = f2bf(y); o.u[2] = f2bf(z); o.u[3] = f2bf(w);
    ((uint2*)dst)[i] = o.v2;
  }
}

// ---------------------------------------------------------------------------
// K3: W1 [1024][512] fp32 -> W1T bf16 [512][1024]
// ---------------------------------------------------------------------------
__global__ __launch_bounds__(256)
void transpose_w1(const float* __restrict__ w1, unsigned short* __restrict__ w1t) {
  __shared__ float tile[32][33];
  int tx = threadIdx.x & 31, ty = threadIdx.x >> 5;  // ty 0..7
  int kb = blockIdx.y * 32, nb = blockIdx.x * 32;
  #pragma unroll
  for (int rr = 0; rr < 32; rr += 8)
    tile[ty + rr][tx] = w1[(size_t)(kb + ty + rr) * 512 + nb + tx];
  __syncthreads();
  #pragma unroll
  for (int rr = 0; rr < 32; rr += 8)
    w1t[(size_t)(nb + ty + rr) * 1024 + kb + tx] = f2bf(tile[tx][ty + rr]);
}

// ---------------------------------------------------------------------------
// K4/K7: NT GEMM bf16 -> fp32.  C[M,Nc] = A[M,K] * B[N,K]^T  (+bias, relu)
// 128x128 tile, BK=64, 4 waves (2x2), mfma_f32_16x16x32_bf16,
// global_load_lds width-16 staging with XOR-chunk swizzle.
// ---------------------------------------------------------------------------
template <int EPI>
__global__ __launch_bounds__(256, 2)
void gemm_nt(const unsigned short* __restrict__ A, const unsigned short* __restrict__ B,
             float* __restrict__ C, const float* __restrict__ bias,
             int M, int N, int K, int Nc) {
  __shared__ __align__(16) uint8_t smem[32768];  // A: 16KB, B: 16KB
  const int tid = threadIdx.x;
  const int lane = tid & 63;
  const int wv = tid >> 6;
  const int wm = wv >> 1, wn = wv & 1;
  const int m0 = blockIdx.y * 128;
  const int n0 = blockIdx.x * 128;
  const int rbytes = K * 2;

  f32x4 acc[4][4];
  #pragma unroll
  for (int i = 0; i < 4; ++i)
    #pragma unroll
    for (int j = 0; j < 4; ++j) acc[i][j] = (f32x4){0.f, 0.f, 0.f, 0.f};

  const int srow = lane >> 3;   // row within 8-row chunk
  const int scol = lane & 7;    // dest 16B unit within row
  const int nkt = K >> 6;       // K / 64

  for (int kt = 0; kt < nkt; ++kt) {
    #pragma unroll
    for (int j = 0; j < 4; ++j) {
      int chunk = wv * 4 + j;
      int r = chunk * 8 + srow;
      int c = scol ^ (r & 7);
      const uint8_t* ga = (const uint8_t*)A + (size_t)(m0 + r) * rbytes + kt * 128 + c * 16;
      gload16(ga, &smem[chunk * 1024]);
      const uint8_t* gb = (const uint8_t*)B + (size_t)(n0 + r) * rbytes + kt * 128 + c * 16;
      gload16(gb, &smem[16384 + chunk * 1024]);
    }
    __syncthreads();
    #pragma unroll
    for (int kk = 0; kk < 2; ++kk) {
      s16x8 af[4], bfr[4];
      #pragma unroll
      for (int f = 0; f < 4; ++f) {
        int ra = wm * 64 + f * 16 + (lane & 15);
        int ca = (kk * 4 + (lane >> 4)) ^ (ra & 7);
        af[f] = *(const s16x8*)&smem[ra * 128 + ca * 16];
        int rb = wn * 64 + f * 16 + (lane & 15);
        int cb = (kk * 4 + (lane >> 4)) ^ (rb & 7);
        bfr[f] = *(const s16x8*)&smem[16384 + rb * 128 + cb * 16];
      }
      #pragma unroll
      for (int fm = 0; fm < 4; ++fm)
        #pragma unroll
        for (int fn = 0; fn < 4; ++fn)
          acc[fm][fn] = __builtin_amdgcn_mfma_f32_16x16x32_bf16(
              af[fm], bfr[fn], acc[fm][fn], 0, 0, 0);
    }
    __syncthreads();
  }

  const int rl = lane >> 4, cl = lane & 15;
  #pragma unroll
  for (int fm = 0; fm < 4; ++fm)
    #pragma unroll
    for (int fn = 0; fn < 4; ++fn)
      #pragma unroll
      for (int j = 0; j < 4; ++j) {
        int gm = m0 + wm * 64 + fm * 16 + rl * 4 + j;
        int gn = n0 + wn * 64 + fn * 16 + cl;
        if (gn < Nc) {
          float v = acc[fm][fn][j];
          if (EPI) v = fmaxf(v + bias[gn], 0.f);
          C[(size_t)gm * Nc + gn] = v;
        }
      }
}

// ---------------------------------------------------------------------------
// K5: logits = HID @ W2 + b2; softmax -> attn (fp32, into d_out)
// ---------------------------------------------------------------------------
__global__ __launch_bounds__(256)
void attn_softmax(const float* __restrict__ hid, const float* __restrict__ w2,
                  const float* __restrict__ b2, float* __restrict__ attn_out) {
  int b = blockIdx.x, tid = threadIdx.x;
  float acc[8] = {0, 0, 0, 0, 0, 0, 0, 0};
  for (int k = tid; k < DCOL; k += 256) {
    float hv = hid[(size_t)b * DCOL + k];
    #pragma unroll
    for (int c = 0; c < 8; ++c) acc[c] += hv * w2[k * 8 + c];
  }
  __shared__ float red[256];
  __shared__ float logits[8];
  for (int c = 0; c < 8; ++c) {
    red[tid] = acc[c]; __syncthreads();
    for (int s = 128; s > 0; s >>= 1) {
      if (tid < s) red[tid] += red[tid + s];
      __syncthreads();
    }
    if (tid == 0) logits[c] = red[0] + b2[c];
    __syncthreads();
  }
  if (tid == 0) {
    float mx = logits[0];
    #pragma unroll
    for (int c = 1; c < 8; ++c) mx = fmaxf(mx, logits[c]);
    float e[8]; float s = 0.f;
    #pragma unroll
    for (int c = 0; c < 8; ++c) { e[c] = expf(logits[c] - mx); s += e[c]; }
    #pragma unroll
    for (int c = 0; c < 8; ++c) attn_out[(size_t)b * 8 + c] = e[c] / s;
  }
}

// ---------------------------------------------------------------------------
// K6: per-triple core contraction. Weff = sum_c attn*Wc (3 permuted LDS
// copies), x1 -> bf16 ws; n2[b] = |x1|^2+|x2|^2+|x3|^2
// ---------------------------------------------------------------------------
__global__ __launch_bounds__(256)
void triple_core(const int* __restrict__ heads, const int* __restrict__ rels,
                 const int* __restrict__ tails, const float* __restrict__ ew,
                 const float* __restrict__ rw, const float* __restrict__ wc,
                 const float* __restrict__ attn, unsigned short* __restrict__ x1b,
                 float* __restrict__ n2) {
  __shared__ float hs[512], rs[512], ts[512];
  __shared__ float W1L[4096], W2L[4096], W3L[4096];
  __shared__ float att[8];
  __shared__ float red[256];
  int b = blockIdx.x, tid = threadIdx.x;
  const float* hp_ = ew + (size_t)heads[b] * DCOL;
  const float* rp_ = rw + (size_t)rels[b] * DCOL;
  const float* tp_ = ew + (size_t)tails[b] * DCOL;
  for (int d = tid; d < DCOL; d += 256) {
    hs[d] = hp_[d]; rs[d] = rp_[d]; ts[d] = tp_[d];
  }
  if (tid < 8) att[tid] = attn[(size_t)b * 8 + tid];
  __syncthreads();
  for (int idx = tid; idx < 4096; idx += 256) {
    float w = 0.f;
    #pragma unroll
    for (int c = 0; c < 8; ++c) w += att[c] * wc[c * 4096 + idx];
    int s = idx & 15, q = (idx >> 4) & 15, p = idx >> 8;
    W1L[idx] = w;                       // [p][q][s]
    W2L[(q * 16 + s) * 16 + p] = w;     // [q][s][p]
    W3L[(p * 16 + s) * 16 + q] = w;     // [p][s][q]
  }
  __syncthreads();

  int so = tid & 15;
  int i0 = tid >> 4;
  float n2acc = 0.f;
  for (int ir = 0; ir < 2; ++ir) {
    int i = i0 + ir * 16;
    float hh[16], rr[16], tt[16];
    #pragma unroll
    for (int k = 0; k < 16; ++k) {
      hh[k] = hs[i * 16 + k]; rr[k] = rs[i * 16 + k]; tt[k] = ts[i * 16 + k];
    }
    float a1 = 0.f, a2 = 0.f, a3 = 0.f;
    #pragma unroll
    for (int p = 0; p < 16; ++p) {
      float hp = hh[p];
      #pragma unroll
      for (int q = 0; q < 16; ++q)
        a1 += hp * rr[q] * W1L[(p * 16 + q) * 16 + so];
    }
    #pragma unroll
    for (int q = 0; q < 16; ++q) {
      float rq = rr[q];
      #pragma unroll
      for (int s2 = 0; s2 < 16; ++s2)
        a2 += rq * tt[s2] * W2L[(q * 16 + s2) * 16 + so];
    }
    #pragma unroll
    for (int p = 0; p < 16; ++p) {
      float hp = hh[p];
      #pragma unroll
      for (int s2 = 0; s2 < 16; ++s2)
        a3 += hp * tt[s2] * W3L[(p * 16 + s2) * 16 + so];
    }
    x1b[(size_t)b * 512 + i * 16 + so] = f2bf(a1);
    n2acc += a1 * a1 + a2 * a2 + a3 * a3;
  }
  red[tid] = n2acc; __syncthreads();
  for (int s = 128; s > 0; s >>= 1) {
    if (tid < s) red[tid] += red[tid + s];
    __syncthreads();
  }
  if (tid == 0) n2[b] = red[0];
}

// ---------------------------------------------------------------------------
// K8: factors. factor1 = sum(n1)/B; factor2 = sum(n2)/B; factor3 geometric.
// ---------------------------------------------------------------------------
__global__ __launch_bounds__(256)
void finalize(const float* __restrict__ n1, const float* __restrict__ n2,
              const float* __restrict__ wc, float* __restrict__ out) {
  int tid = threadIdx.x;
  __shared__ float red[256];
  float a = 0.f;
  for (int i = tid; i < NB; i += 256) a += n1[i];
  red[tid] = a; __syncthreads();
  for (int s = 128; s > 0; s >>= 1) { if (tid < s) red[tid] += red[tid + s]; __syncthreads(); }
  if (tid == 0) out[F1_OFF] = red[0] / (float)NB;
  __syncthreads();
  a = 0.f;
  for (int i = tid; i < NB; i += 256) a += n2[i];
  red[tid] = a; __syncthreads();
  for (int s = 128; s > 0; s >>= 1) { if (tid < s) red[tid] += red[tid + s]; __syncthreads(); }
  if (tid == 0) out[F2_OFF] = red[0] / (float)NB;
  __syncthreads();

  // factor3: 32 lanes per core
  int c = tid >> 5, l = tid & 31;
  float tot = 0.f, cx = 0.f, cy = 0.f, cz = 0.f;
  for (int e = l; e < 4096; e += 32) {
    float w = fabsf(wc[c * 4096 + e]);
    int z = e & 15, y = (e >> 4) & 15, x = e >> 8;
    tot += w; cx += w * x; cy += w * y; cz += w * z;
  }
  #pragma unroll
  for (int off = 16; off > 0; off >>= 1) {
    tot += __shfl_down(tot, off);
    cx += __shfl_down(cx, off);
    cy += __shfl_down(cy, off);
    cz += __shfl_down(cz, off);
  }
  __shared__ float cent[8][3];
  if (l == 0) { cent[c][0] = cx / tot; cent[c][1] = cy / tot; cent[c][2] = cz / tot; }
  __syncthreads();
  if (tid == 0) {
    float f3 = 0.f;
    for (int i = 0; i < 8; ++i) {
      float mn = 1e30f;
      for (int j = 0; j < 8; ++j) {
        if (j == i) continue;
        float dx = cent[i][0] - cent[j][0];
        float dy = cent[i][1] - cent[j][1];
        float dz = cent[i][2] - cent[j][2];
        float d = sqrtf(dx * dx + dy * dy + dz * dz);
        mn = fminf(mn, d);
      }
      f3 += logf(mn + 1e-6f);
    }
    out[F3_OFF] = -f3 / 8.f;
  }
}

// ---------------------------------------------------------------------------
extern "C" void kernel_launch(void* const* d_in, const int* in_sizes, int n_in,
                              void* d_out, int out_size, void* d_ws, size_t ws_size,
                              hipStream_t stream) {
  const int* heads = (const int*)d_in[0];
  const int* rels = (const int*)d_in[1];
  const int* tails = (const int*)d_in[2];
  const float* ew = (const float*)d_in[3];
  const float* rw = (const float*)d_in[4];
  const float* wc = (const float*)d_in[5];
  const float* w1 = (const float*)d_in[6];
  const float* b1 = (const float*)d_in[7];
  const float* w2 = (const float*)d_in[8];
  const float* b2 = (const float*)d_in[9];
  float* out = (float*)d_out;

  uint8_t* ws = (uint8_t*)d_ws;
  const size_t EWB_SZ = (size_t)NE_PAD * DCOL * 2;   // 51,249,152
  unsigned short* ewb = (unsigned short*)ws;
  unsigned short* hrb = (unsigned short*)(ws + EWB_SZ);
  unsigned short* w1t = (unsigned short*)(ws + EWB_SZ + 2097152);
  float* hid = (float*)(ws + EWB_SZ + 2097152 + 1048576);
  unsigned short* x1b = (unsigned short*)(ws + EWB_SZ + 2097152 + 1048576 + 2097152);
  float* n1 = (float*)(ws + EWB_SZ + 2097152 + 1048576 + 2097152 + 1048576);
  float* n2 = n1 + NB;

  gather_hr<<<NB, 256, 0, stream>>>(heads, rels, tails, ew, rw, hrb, n1);
  cvt_pad<<<2048, 256, 0, stream>>>(ew, ewb, NE * DCOL / 4, NE_PAD * DCOL / 4);
  transpose_w1<<<dim3(16, 32), 256, 0, stream>>>(w1, w1t);
  gemm_nt<1><<<dim3(4, 8), 256, 0, stream>>>(hrb, w1t, hid, b1, 1024, 512, 1024, 512);
  attn_softmax<<<NB, 256, 0, stream>>>(hid, w2, b2, out + ATTN_OFF);
  triple_core<<<NB, 256, 0, stream>>>(heads, rels, tails, ew, rw, wc,
                                      out + ATTN_OFF, x1b, n2);
  gemm_nt<0><<<dim3(NE_PAD / 128, 8), 256, 0, stream>>>(x1b, ewb, out, nullptr,
                                                        1024, NE_PAD, 512, NE);
  finalize<<<1, 256, 0, stream>>>(n1, n2, wc, out);
}

// Round 2
// 300.229 us; speedup vs baseline: 1.6860x; 1.6860x over previous
//
#include <hip/hip_runtime.h>
#include <cstdint>
#include <cstddef>

// Problem constants
#define NB 1024        // batch of triples
#define NE 50000       // entities
#define NE_PAD 50048   // padded to 391*128
#define DCOL 512       // dimension D
#define ATTN_C 8       // cores

static const size_t SCORES_OFF = (size_t)NB * NE;        // 51,200,000
static const size_t F1_OFF = SCORES_OFF + 0;
static const size_t F2_OFF = SCORES_OFF + 1;
static const size_t F3_OFF = SCORES_OFF + 2;
static const size_t ATTN_OFF = SCORES_OFF + 3;

typedef float f32x4 __attribute__((ext_vector_type(4)));
typedef short s16x8 __attribute__((ext_vector_type(8)));

__device__ __forceinline__ unsigned short f2bf(float f) {
  union { float f; uint32_t u; } x; x.f = f;
  uint32_t u = x.u;
  uint32_t r = (u + 0x7fffu + ((u >> 16) & 1u)) >> 16;  // RNE
  return (unsigned short)r;
}

__device__ __forceinline__ void gload16(const void* g, void* l) {
  __builtin_amdgcn_global_load_lds(
      (const __attribute__((address_space(1))) uint32_t*)g,
      (__attribute__((address_space(3))) uint32_t*)l, 16, 0, 0);
}

// ---------------------------------------------------------------------------
// K1: gather h,r,t -> HR bf16 [NB][1024]; n1[b] = |h|^2+|r|^2+|t|^2
// ---------------------------------------------------------------------------
__global__ __launch_bounds__(256)
void gather_hr(const int* __restrict__ heads, const int* __restrict__ rels,
               const int* __restrict__ tails, const float* __restrict__ ew,
               const float* __restrict__ rw, unsigned short* __restrict__ hrb,
               float* __restrict__ n1) {
  int b = blockIdx.x, tid = threadIdx.x;
  const float* h = ew + (size_t)heads[b] * DCOL;
  const float* r = rw + (size_t)rels[b] * DCOL;
  const float* t = ew + (size_t)tails[b] * DCOL;
  float acc = 0.f;
  for (int d = tid; d < DCOL; d += 256) {
    float hv = h[d], rv = r[d], tv = t[d];
    hrb[(size_t)b * 1024 + d] = f2bf(hv);
    hrb[(size_t)b * 1024 + DCOL + d] = f2bf(rv);
    acc += hv * hv + rv * rv + tv * tv;
  }
  __shared__ float red[256];
  red[tid] = acc; __syncthreads();
  for (int s = 128; s > 0; s >>= 1) {
    if (tid < s) red[tid] += red[tid + s];
    __syncthreads();
  }
  if (tid == 0) n1[b] = red[0];
}

// ---------------------------------------------------------------------------
// K2: entity_w fp32 -> bf16, padded rows zeroed. Processes 4 elems/thread.
// ---------------------------------------------------------------------------
__global__ __launch_bounds__(256)
void cvt_pad(const float* __restrict__ src, unsigned short* __restrict__ dst,
             int n4valid, int n4tot) {
  int i = blockIdx.x * 256 + threadIdx.x;
  int stride = gridDim.x * 256;
  for (; i < n4tot; i += stride) {
    float x = 0.f, y = 0.f, z = 0.f, w = 0.f;
    if (i < n4valid) {
      float4 v = ((const float4*)src)[i];
      x = v.x; y = v.y; z = v.z; w = v.w;
    }
    union { unsigned short u[4]; uint2 v2; } o;
    o.u[0] = f2bf(x); o.u[1] = f2bf(y); o.u[2] = f2bf(z); o.u[3] = f2bf(w);
    ((uint2*)dst)[i] = o.v2;
  }
}

// ---------------------------------------------------------------------------
// K3: W1 [1024][512] fp32 -> W1T bf16 [512][1024]
// ---------------------------------------------------------------------------
__global__ __launch_bounds__(256)
void transpose_w1(const float* __restrict__ w1, unsigned short* __restrict__ w1t) {
  __shared__ float tile[32][33];
  int tx = threadIdx.x & 31, ty = threadIdx.x >> 5;  // ty 0..7
  int kb = blockIdx.y * 32, nb = blockIdx.x * 32;
  #pragma unroll
  for (int rr = 0; rr < 32; rr += 8)
    tile[ty + rr][tx] = w1[(size_t)(kb + ty + rr) * 512 + nb + tx];
  __syncthreads();
  #pragma unroll
  for (int rr = 0; rr < 32; rr += 8)
    w1t[(size_t)(nb + ty + rr) * 1024 + kb + tx] = f2bf(tile[tx][ty + rr]);
}

// ---------------------------------------------------------------------------
// K4/K7: NT GEMM bf16 -> fp32.  C[M,Nc] = A[M,K] * B[N,K]^T  (+bias, relu)
// 128x128 tile, BK=64, 4 waves (2x2), mfma_f32_16x16x32_bf16,
// global_load_lds width-16 staging with XOR-chunk swizzle.
// ---------------------------------------------------------------------------
template <int EPI>
__global__ __launch_bounds__(256, 2)
void gemm_nt(const unsigned short* __restrict__ A, const unsigned short* __restrict__ B,
             float* __restrict__ C, const float* __restrict__ bias,
             int M, int N, int K, int Nc) {
  __shared__ __align__(16) uint8_t smem[32768];  // A: 16KB, B: 16KB
  const int tid = threadIdx.x;
  const int lane = tid & 63;
  const int wv = tid >> 6;
  const int wm = wv >> 1, wn = wv & 1;
  const int m0 = blockIdx.y * 128;
  const int n0 = blockIdx.x * 128;
  const int rbytes = K * 2;

  f32x4 acc[4][4];
  #pragma unroll
  for (int i = 0; i < 4; ++i)
    #pragma unroll
    for (int j = 0; j < 4; ++j) acc[i][j] = (f32x4){0.f, 0.f, 0.f, 0.f};

  const int srow = lane >> 3;   // row within 8-row chunk
  const int scol = lane & 7;    // dest 16B unit within row
  const int nkt = K >> 6;       // K / 64

  for (int kt = 0; kt < nkt; ++kt) {
    #pragma unroll
    for (int j = 0; j < 4; ++j) {
      int chunk = wv * 4 + j;
      int r = chunk * 8 + srow;
      int c = scol ^ (r & 7);
      const uint8_t* ga = (const uint8_t*)A + (size_t)(m0 + r) * rbytes + kt * 128 + c * 16;
      gload16(ga, &smem[chunk * 1024]);
      const uint8_t* gb = (const uint8_t*)B + (size_t)(n0 + r) * rbytes + kt * 128 + c * 16;
      gload16(gb, &smem[16384 + chunk * 1024]);
    }
    __syncthreads();
    #pragma unroll
    for (int kk = 0; kk < 2; ++kk) {
      s16x8 af[4], bfr[4];
      #pragma unroll
      for (int f = 0; f < 4; ++f) {
        int ra = wm * 64 + f * 16 + (lane & 15);
        int ca = (kk * 4 + (lane >> 4)) ^ (ra & 7);
        af[f] = *(const s16x8*)&smem[ra * 128 + ca * 16];
        int rb = wn * 64 + f * 16 + (lane & 15);
        int cb = (kk * 4 + (lane >> 4)) ^ (rb & 7);
        bfr[f] = *(const s16x8*)&smem[16384 + rb * 128 + cb * 16];
      }
      #pragma unroll
      for (int fm = 0; fm < 4; ++fm)
        #pragma unroll
        for (int fn = 0; fn < 4; ++fn)
          acc[fm][fn] = __builtin_amdgcn_mfma_f32_16x16x32_bf16(
              af[fm], bfr[fn], acc[fm][fn], 0, 0, 0);
    }
    __syncthreads();
  }

  const int rl = lane >> 4, cl = lane & 15;
  #pragma unroll
  for (int fm = 0; fm < 4; ++fm)
    #pragma unroll
    for (int fn = 0; fn < 4; ++fn)
      #pragma unroll
      for (int j = 0; j < 4; ++j) {
        int gm = m0 + wm * 64 + fm * 16 + rl * 4 + j;
        int gn = n0 + wn * 64 + fn * 16 + cl;
        if (gn < Nc) {
          float v = acc[fm][fn][j];
          if (EPI) v = fmaxf(v + bias[gn], 0.f);
          C[(size_t)gm * Nc + gn] = v;
        }
      }
}

// ---------------------------------------------------------------------------
// K5: logits = HID @ W2 + b2; softmax -> attn (fp32, into d_out)
// ---------------------------------------------------------------------------
__global__ __launch_bounds__(256)
void attn_softmax(const float* __restrict__ hid, const float* __restrict__ w2,
                  const float* __restrict__ b2, float* __restrict__ attn_out) {
  int b = blockIdx.x, tid = threadIdx.x;
  float acc[8] = {0, 0, 0, 0, 0, 0, 0, 0};
  for (int k = tid; k < DCOL; k += 256) {
    float hv = hid[(size_t)b * DCOL + k];
    #pragma unroll
    for (int c = 0; c < 8; ++c) acc[c] += hv * w2[k * 8 + c];
  }
  __shared__ float red[256];
  __shared__ float logits[8];
  for (int c = 0; c < 8; ++c) {
    red[tid] = acc[c]; __syncthreads();
    for (int s = 128; s > 0; s >>= 1) {
      if (tid < s) red[tid] += red[tid + s];
      __syncthreads();
    }
    if (tid == 0) logits[c] = red[0] + b2[c];
    __syncthreads();
  }
  if (tid == 0) {
    float mx = logits[0];
    #pragma unroll
    for (int c = 1; c < 8; ++c) mx = fmaxf(mx, logits[c]);
    float e[8]; float s = 0.f;
    #pragma unroll
    for (int c = 0; c < 8; ++c) { e[c] = expf(logits[c] - mx); s += e[c]; }
    #pragma unroll
    for (int c = 0; c < 8; ++c) attn_out[(size_t)b * 8 + c] = e[c] / s;
  }
}

// ---------------------------------------------------------------------------
// K6: per-triple core contraction, v2 (no-spill).
// 512 threads: thread = (i = tid>>4 in 0..31, so = tid&15).
// Weff built once into 3 permuted LDS copies so all three contraction terms
// share ONE LDS offset per (u,v) iteration:
//   a1 += h[u]*r[v]*W1L[(u,v),so]   W1L = Weff[p][q][s]   (u=p, v=q, so=s)
//   a2 += r[u]*t[v]*W2L[(u,v),so]   W2L = Weff[q][s][p]   (u=q, v=s, so=p)
//   a3 += h[u]*t[v]*W3L[(u,v),so]   W3L = Weff[p][s][q]   (u=p, v=s, so=q)
// 48 register floats + 3 accumulators -> no scratch.
// ---------------------------------------------------------------------------
__global__ __launch_bounds__(512, 4)
void triple_core(const int* __restrict__ heads, const int* __restrict__ rels,
                 const int* __restrict__ tails, const float* __restrict__ ew,
                 const float* __restrict__ rw, const float* __restrict__ wc,
                 const float* __restrict__ attn, unsigned short* __restrict__ x1b,
                 float* __restrict__ n2) {
  __shared__ float hs[512], rs[512], ts[512];
  __shared__ float W1L[4096], W2L[4096], W3L[4096];
  __shared__ float att[8];
  __shared__ float red[512];
  int b = blockIdx.x, tid = threadIdx.x;
  const float* hp_ = ew + (size_t)heads[b] * DCOL;
  const float* rp_ = rw + (size_t)rels[b] * DCOL;
  const float* tp_ = ew + (size_t)tails[b] * DCOL;
  if (tid < 512) {
    hs[tid] = hp_[tid]; rs[tid] = rp_[tid]; ts[tid] = tp_[tid];
  }
  if (tid < 8) att[tid] = attn[(size_t)b * 8 + tid];
  __syncthreads();
  #pragma unroll
  for (int it = 0; it < 8; ++it) {
    int idx = it * 512 + tid;
    float w = 0.f;
    #pragma unroll
    for (int c = 0; c < 8; ++c) w += att[c] * wc[c * 4096 + idx];
    int s = idx & 15, q = (idx >> 4) & 15, p = idx >> 8;
    W1L[idx] = w;                       // [p][q][s]
    W2L[(q * 16 + s) * 16 + p] = w;     // [q][s][p]
    W3L[(p * 16 + s) * 16 + q] = w;     // [p][s][q]
  }
  __syncthreads();

  const int so = tid & 15;
  const int i = tid >> 4;           // 0..31
  float hh[16], rr[16], tt[16];
  #pragma unroll
  for (int k = 0; k < 16; ++k) {
    hh[k] = hs[i * 16 + k]; rr[k] = rs[i * 16 + k]; tt[k] = ts[i * 16 + k];
  }
  float a1 = 0.f, a2 = 0.f, a3 = 0.f;
  #pragma unroll 4
  for (int u = 0; u < 16; ++u) {
    float hu = hh[u], ru = rr[u];
    #pragma unroll
    for (int v = 0; v < 16; ++v) {
      int off = (u * 16 + v) * 16 + so;
      float rv = rr[v], tv = tt[v];
      a1 = fmaf(hu * rv, W1L[off], a1);
      a2 = fmaf(ru * tv, W2L[off], a2);
      a3 = fmaf(hu * tv, W3L[off], a3);
    }
  }
  x1b[(size_t)b * 512 + i * 16 + so] = f2bf(a1);
  float n2acc = a1 * a1 + a2 * a2 + a3 * a3;
  red[tid] = n2acc; __syncthreads();
  for (int s = 256; s > 0; s >>= 1) {
    if (tid < s) red[tid] += red[tid + s];
    __syncthreads();
  }
  if (tid == 0) n2[b] = red[0];
}

// ---------------------------------------------------------------------------
// K8: factors. factor1 = sum(n1)/B; factor2 = sum(n2)/B; factor3 geometric.
// ---------------------------------------------------------------------------
__global__ __launch_bounds__(256)
void finalize(const float* __restrict__ n1, const float* __restrict__ n2,
              const float* __restrict__ wc, float* __restrict__ out) {
  int tid = threadIdx.x;
  __shared__ float red[256];
  float a = 0.f;
  for (int i = tid; i < NB; i += 256) a += n1[i];
  red[tid] = a; __syncthreads();
  for (int s = 128; s > 0; s >>= 1) { if (tid < s) red[tid] += red[tid + s]; __syncthreads(); }
  if (tid == 0) out[F1_OFF] = red[0] / (float)NB;
  __syncthreads();
  a = 0.f;
  for (int i = tid; i < NB; i += 256) a += n2[i];
  red[tid] = a; __syncthreads();
  for (int s = 128; s > 0; s >>= 1) { if (tid < s) red[tid] += red[tid + s]; __syncthreads(); }
  if (tid == 0) out[F2_OFF] = red[0] / (float)NB;
  __syncthreads();

  // factor3: 32 lanes per core
  int c = tid >> 5, l = tid & 31;
  float tot = 0.f, cx = 0.f, cy = 0.f, cz = 0.f;
  for (int e = l; e < 4096; e += 32) {
    float w = fabsf(wc[c * 4096 + e]);
    int z = e & 15, y = (e >> 4) & 15, x = e >> 8;
    tot += w; cx += w * x; cy += w * y; cz += w * z;
  }
  #pragma unroll
  for (int off = 16; off > 0; off >>= 1) {
    tot += __shfl_down(tot, off);
    cx += __shfl_down(cx, off);
    cy += __shfl_down(cy, off);
    cz += __shfl_down(cz, off);
  }
  __shared__ float cent[8][3];
  if (l == 0) { cent[c][0] = cx / tot; cent[c][1] = cy / tot; cent[c][2] = cz / tot; }
  __syncthreads();
  if (tid == 0) {
    float f3 = 0.f;
    for (int i = 0; i < 8; ++i) {
      float mn = 1e30f;
      for (int j = 0; j < 8; ++j) {
        if (j == i) continue;
        float dx = cent[i][0] - cent[j][0];
        float dy = cent[i][1] - cent[j][1];
        float dz = cent[i][2] - cent[j][2];
        float d = sqrtf(dx * dx + dy * dy + dz * dz);
        mn = fminf(mn, d);
      }
      f3 += logf(mn + 1e-6f);
    }
    out[F3_OFF] = -f3 / 8.f;
  }
}

// ---------------------------------------------------------------------------
extern "C" void kernel_launch(void* const* d_in, const int* in_sizes, int n_in,
                              void* d_out, int out_size, void* d_ws, size_t ws_size,
                              hipStream_t stream) {
  const int* heads = (const int*)d_in[0];
  const int* rels = (const int*)d_in[1];
  const int* tails = (const int*)d_in[2];
  const float* ew = (const float*)d_in[3];
  const float* rw = (const float*)d_in[4];
  const float* wc = (const float*)d_in[5];
  const float* w1 = (const float*)d_in[6];
  const float* b1 = (const float*)d_in[7];
  const float* w2 = (const float*)d_in[8];
  const float* b2 = (const float*)d_in[9];
  float* out = (float*)d_out;

  uint8_t* ws = (uint8_t*)d_ws;
  const size_t EWB_SZ = (size_t)NE_PAD * DCOL * 2;   // 51,249,152
  unsigned short* ewb = (unsigned short*)ws;
  unsigned short* hrb = (unsigned short*)(ws + EWB_SZ);
  unsigned short* w1t = (unsigned short*)(ws + EWB_SZ + 2097152);
  float* hid = (float*)(ws + EWB_SZ + 2097152 + 1048576);
  unsigned short* x1b = (unsigned short*)(ws + EWB_SZ + 2097152 + 1048576 + 2097152);
  float* n1 = (float*)(ws + EWB_SZ + 2097152 + 1048576 + 2097152 + 1048576);
  float* n2 = n1 + NB;

  gather_hr<<<NB, 256, 0, stream>>>(heads, rels, tails, ew, rw, hrb, n1);
  cvt_pad<<<2048, 256, 0, stream>>>(ew, ewb, NE * DCOL / 4, NE_PAD * DCOL / 4);
  transpose_w1<<<dim3(16, 32), 256, 0, stream>>>(w1, w1t);
  gemm_nt<1><<<dim3(4, 8), 256, 0, stream>>>(hrb, w1t, hid, b1, 1024, 512, 1024, 512);
  attn_softmax<<<NB, 256, 0, stream>>>(hid, w2, b2, out + ATTN_OFF);
  triple_core<<<NB, 512, 0, stream>>>(heads, rels, tails, ew, rw, wc,
                                      out + ATTN_OFF, x1b, n2);
  gemm_nt<0><<<dim3(NE_PAD / 128, 8), 256, 0, stream>>>(x1b, ewb, out, nullptr,
                                                        1024, NE_PAD, 512, NE);
  finalize<<<1, 256, 0, stream>>>(n1, n2, wc, out);
}

// Round 3
// 253.233 us; speedup vs baseline: 1.9988x; 1.1856x over previous
//
#include <hip/hip_runtime.h>
#include <cstdint>
#include <cstddef>

// Problem constants
#define NB 1024        // batch of triples
#define NE 50000       // entities
#define NE_PAD 50048   // padded to 391*128
#define DCOL 512       // dimension D
#define ATTN_C 8       // cores

static const size_t SCORES_OFF = (size_t)NB * NE;        // 51,200,000
static const size_t F1_OFF = SCORES_OFF + 0;
static const size_t F2_OFF = SCORES_OFF + 1;
static const size_t F3_OFF = SCORES_OFF + 2;
static const size_t ATTN_OFF = SCORES_OFF + 3;

typedef float f32x4 __attribute__((ext_vector_type(4)));
typedef short s16x8 __attribute__((ext_vector_type(8)));

__device__ __forceinline__ unsigned short f2bf(float f) {
  union { float f; uint32_t u; } x; x.f = f;
  uint32_t u = x.u;
  uint32_t r = (u + 0x7fffu + ((u >> 16) & 1u)) >> 16;  // RNE
  return (unsigned short)r;
}

__device__ __forceinline__ void gload16(const void* g, void* l) {
  __builtin_amdgcn_global_load_lds(
      (const __attribute__((address_space(1))) uint32_t*)g,
      (__attribute__((address_space(3))) uint32_t*)l, 16, 0, 0);
}

// ---------------------------------------------------------------------------
// K1: gather h,r,t -> HR bf16 [NB][1024]; n1[b] = |h|^2+|r|^2+|t|^2
// ---------------------------------------------------------------------------
__global__ __launch_bounds__(256)
void gather_hr(const int* __restrict__ heads, const int* __restrict__ rels,
               const int* __restrict__ tails, const float* __restrict__ ew,
               const float* __restrict__ rw, unsigned short* __restrict__ hrb,
               float* __restrict__ n1) {
  int b = blockIdx.x, tid = threadIdx.x;
  const float* h = ew + (size_t)heads[b] * DCOL;
  const float* r = rw + (size_t)rels[b] * DCOL;
  const float* t = ew + (size_t)tails[b] * DCOL;
  float acc = 0.f;
  for (int d = tid; d < DCOL; d += 256) {
    float hv = h[d], rv = r[d], tv = t[d];
    hrb[(size_t)b * 1024 + d] = f2bf(hv);
    hrb[(size_t)b * 1024 + DCOL + d] = f2bf(rv);
    acc += hv * hv + rv * rv + tv * tv;
  }
  __shared__ float red[256];
  red[tid] = acc; __syncthreads();
  for (int s = 128; s > 0; s >>= 1) {
    if (tid < s) red[tid] += red[tid + s];
    __syncthreads();
  }
  if (tid == 0) n1[b] = red[0];
}

// ---------------------------------------------------------------------------
// K2: entity_w fp32 -> bf16, padded rows zeroed. Processes 4 elems/thread.
// ---------------------------------------------------------------------------
__global__ __launch_bounds__(256)
void cvt_pad(const float* __restrict__ src, unsigned short* __restrict__ dst,
             int n4valid, int n4tot) {
  int i = blockIdx.x * 256 + threadIdx.x;
  int stride = gridDim.x * 256;
  for (; i < n4tot; i += stride) {
    float x = 0.f, y = 0.f, z = 0.f, w = 0.f;
    if (i < n4valid) {
      float4 v = ((const float4*)src)[i];
      x = v.x; y = v.y; z = v.z; w = v.w;
    }
    union { unsigned short u[4]; uint2 v2; } o;
    o.u[0] = f2bf(x); o.u[1] = f2bf(y); o.u[2] = f2bf(z); o.u[3] = f2bf(w);
    ((uint2*)dst)[i] = o.v2;
  }
}

// ---------------------------------------------------------------------------
// K3: W1 [1024][512] fp32 -> W1T bf16 [512][1024]
// ---------------------------------------------------------------------------
__global__ __launch_bounds__(256)
void transpose_w1(const float* __restrict__ w1, unsigned short* __restrict__ w1t) {
  __shared__ float tile[32][33];
  int tx = threadIdx.x & 31, ty = threadIdx.x >> 5;  // ty 0..7
  int kb = blockIdx.y * 32, nb = blockIdx.x * 32;
  #pragma unroll
  for (int rr = 0; rr < 32; rr += 8)
    tile[ty + rr][tx] = w1[(size_t)(kb + ty + rr) * 512 + nb + tx];
  __syncthreads();
  #pragma unroll
  for (int rr = 0; rr < 32; rr += 8)
    w1t[(size_t)(nb + ty + rr) * 1024 + kb + tx] = f2bf(tile[tx][ty + rr]);
}

// ---------------------------------------------------------------------------
// K4/K7: NT GEMM bf16 -> fp32.  C[M,Nc] = A[M,K] * B[N,K]^T  (+bias, relu)
// 128x128 tile, BK=64, 4 waves (2x2), mfma_f32_16x16x32_bf16,
// global_load_lds width-16 staging with XOR-chunk swizzle.
// Grid: x = M-tiles (few), y = N-tiles (many). x-major dispatch makes the
// blocks sharing one B-tile dispatch-adjacent -> B fetched from HBM once.
// ---------------------------------------------------------------------------
template <int EPI>
__global__ __launch_bounds__(256, 2)
void gemm_nt(const unsigned short* __restrict__ A, const unsigned short* __restrict__ B,
             float* __restrict__ C, const float* __restrict__ bias,
             int M, int N, int K, int Nc) {
  __shared__ __align__(16) uint8_t smem[32768];  // A: 16KB, B: 16KB
  const int tid = threadIdx.x;
  const int lane = tid & 63;
  const int wv = tid >> 6;
  const int wm = wv >> 1, wn = wv & 1;
  const int m0 = blockIdx.x * 128;
  const int n0 = blockIdx.y * 128;
  const int rbytes = K * 2;

  f32x4 acc[4][4];
  #pragma unroll
  for (int i = 0; i < 4; ++i)
    #pragma unroll
    for (int j = 0; j < 4; ++j) acc[i][j] = (f32x4){0.f, 0.f, 0.f, 0.f};

  const int srow = lane >> 3;   // row within 8-row chunk
  const int scol = lane & 7;    // dest 16B unit within row
  const int nkt = K >> 6;       // K / 64

  for (int kt = 0; kt < nkt; ++kt) {
    #pragma unroll
    for (int j = 0; j < 4; ++j) {
      int chunk = wv * 4 + j;
      int r = chunk * 8 + srow;
      int c = scol ^ (r & 7);
      const uint8_t* ga = (const uint8_t*)A + (size_t)(m0 + r) * rbytes + kt * 128 + c * 16;
      gload16(ga, &smem[chunk * 1024]);
      const uint8_t* gb = (const uint8_t*)B + (size_t)(n0 + r) * rbytes + kt * 128 + c * 16;
      gload16(gb, &smem[16384 + chunk * 1024]);
    }
    __syncthreads();
    #pragma unroll
    for (int kk = 0; kk < 2; ++kk) {
      s16x8 af[4], bfr[4];
      #pragma unroll
      for (int f = 0; f < 4; ++f) {
        int ra = wm * 64 + f * 16 + (lane & 15);
        int ca = (kk * 4 + (lane >> 4)) ^ (ra & 7);
        af[f] = *(const s16x8*)&smem[ra * 128 + ca * 16];
        int rb = wn * 64 + f * 16 + (lane & 15);
        int cb = (kk * 4 + (lane >> 4)) ^ (rb & 7);
        bfr[f] = *(const s16x8*)&smem[16384 + rb * 128 + cb * 16];
      }
      #pragma unroll
      for (int fm = 0; fm < 4; ++fm)
        #pragma unroll
        for (int fn = 0; fn < 4; ++fn)
          acc[fm][fn] = __builtin_amdgcn_mfma_f32_16x16x32_bf16(
              af[fm], bfr[fn], acc[fm][fn], 0, 0, 0);
    }
    __syncthreads();
  }

  const int rl = lane >> 4, cl = lane & 15;
  #pragma unroll
  for (int fm = 0; fm < 4; ++fm)
    #pragma unroll
    for (int fn = 0; fn < 4; ++fn)
      #pragma unroll
      for (int j = 0; j < 4; ++j) {
        int gm = m0 + wm * 64 + fm * 16 + rl * 4 + j;
        int gn = n0 + wn * 64 + fn * 16 + cl;
        if (gn < Nc) {
          float v = acc[fm][fn][j];
          if (EPI) v = fmaxf(v + bias[gn], 0.f);
          C[(size_t)gm * Nc + gn] = v;
        }
      }
}

// ---------------------------------------------------------------------------
// K5: logits = HID @ W2 + b2; softmax -> attn (fp32, into d_out)
// ---------------------------------------------------------------------------
__global__ __launch_bounds__(256)
void attn_softmax(const float* __restrict__ hid, const float* __restrict__ w2,
                  const float* __restrict__ b2, float* __restrict__ attn_out) {
  int b = blockIdx.x, tid = threadIdx.x;
  float acc[8] = {0, 0, 0, 0, 0, 0, 0, 0};
  for (int k = tid; k < DCOL; k += 256) {
    float hv = hid[(size_t)b * DCOL + k];
    #pragma unroll
    for (int c = 0; c < 8; ++c) acc[c] += hv * w2[k * 8 + c];
  }
  __shared__ float red[256];
  __shared__ float logits[8];
  for (int c = 0; c < 8; ++c) {
    red[tid] = acc[c]; __syncthreads();
    for (int s = 128; s > 0; s >>= 1) {
      if (tid < s) red[tid] += red[tid + s];
      __syncthreads();
    }
    if (tid == 0) logits[c] = red[0] + b2[c];
    __syncthreads();
  }
  if (tid == 0) {
    float mx = logits[0];
    #pragma unroll
    for (int c = 1; c < 8; ++c) mx = fmaxf(mx, logits[c]);
    float e[8]; float s = 0.f;
    #pragma unroll
    for (int c = 0; c < 8; ++c) { e[c] = expf(logits[c] - mx); s += e[c]; }
    #pragma unroll
    for (int c = 0; c < 8; ++c) attn_out[(size_t)b * 8 + c] = e[c] / s;
  }
}

// ---------------------------------------------------------------------------
// K6: per-triple core contraction, v3.
// 256 threads: thread = (i0 = tid>>4 in 0..15, so = tid&15); each thread
// computes output rows i0 and i0+16. W1/W2/W3 interleaved in ONE float4 LDS
// array so each (u,v) iteration is a single ds_read_b128 at an immediate
// offset (base = so*16B):
//   a1 += h[u]*r[v]*W[.x]   ([p][q][s] at (u,v,so))
//   a2 += r[u]*t[v]*W[.y]   ([q][s][p] at (u,v,so))
//   a3 += h[u]*t[v]*W[.z]   ([p][s][q] at (u,v,so))
// BOTH loops fully unrolled -> every register-array index is static (rule
// #20: partial unroll put these arrays in scratch = R1/R2's spill traffic).
// ---------------------------------------------------------------------------
__global__ __launch_bounds__(256, 2)
void triple_core(const int* __restrict__ heads, const int* __restrict__ rels,
                 const int* __restrict__ tails, const float* __restrict__ ew,
                 const float* __restrict__ rw, const float* __restrict__ wc,
                 const float* __restrict__ attn, unsigned short* __restrict__ x1b,
                 float* __restrict__ n2) {
  __shared__ float hs[512], rs[512], ts[512];
  __shared__ __align__(16) float W123[4096][4];   // 64 KB
  __shared__ float att[8];
  __shared__ float red[256];
  int b = blockIdx.x, tid = threadIdx.x;
  const float* hp_ = ew + (size_t)heads[b] * DCOL;
  const float* rp_ = rw + (size_t)rels[b] * DCOL;
  const float* tp_ = ew + (size_t)tails[b] * DCOL;
  #pragma unroll
  for (int it = 0; it < 2; ++it) {
    int d = it * 256 + tid;
    hs[d] = hp_[d]; rs[d] = rp_[d]; ts[d] = tp_[d];
  }
  if (tid < 8) att[tid] = attn[(size_t)b * 8 + tid];
  __syncthreads();
  #pragma unroll
  for (int it = 0; it < 16; ++it) {
    int idx = it * 256 + tid;
    float w = 0.f;
    #pragma unroll
    for (int c = 0; c < 8; ++c) w = fmaf(att[c], wc[c * 4096 + idx], w);
    int s = idx & 15, q = (idx >> 4) & 15, p = idx >> 8;
    W123[idx][0] = w;                     // [p][q][s]
    W123[(q * 16 + s) * 16 + p][1] = w;   // [q][s][p]
    W123[(p * 16 + s) * 16 + q][2] = w;   // [p][s][q]
  }
  __syncthreads();

  const int so = tid & 15;
  const int i0 = tid >> 4, i1 = i0 + 16;
  float h0[16], r0[16], t0[16], h1[16], r1[16], t1[16];
  #pragma unroll
  for (int k = 0; k < 16; ++k) {
    h0[k] = hs[i0 * 16 + k]; r0[k] = rs[i0 * 16 + k]; t0[k] = ts[i0 * 16 + k];
    h1[k] = hs[i1 * 16 + k]; r1[k] = rs[i1 * 16 + k]; t1[k] = ts[i1 * 16 + k];
  }
  float a10 = 0.f, a20 = 0.f, a30 = 0.f, a11 = 0.f, a21 = 0.f, a31 = 0.f;
  const float4* wp = (const float4*)&W123[so][0];   // per-thread base
  #pragma unroll
  for (int u = 0; u < 16; ++u) {
    #pragma unroll
    for (int v = 0; v < 16; ++v) {
      float4 w = wp[u * 256 + v * 16];   // byte off = u*4096+v*256 (imm)
      a10 = fmaf(h0[u] * r0[v], w.x, a10);
      a20 = fmaf(r0[u] * t0[v], w.y, a20);
      a30 = fmaf(h0[u] * t0[v], w.z, a30);
      a11 = fmaf(h1[u] * r1[v], w.x, a11);
      a21 = fmaf(r1[u] * t1[v], w.y, a21);
      a31 = fmaf(h1[u] * t1[v], w.z, a31);
    }
  }
  x1b[(size_t)b * 512 + i0 * 16 + so] = f2bf(a10);
  x1b[(size_t)b * 512 + i1 * 16 + so] = f2bf(a11);
  red[tid] = a10 * a10 + a20 * a20 + a30 * a30
           + a11 * a11 + a21 * a21 + a31 * a31;
  __syncthreads();
  for (int s = 128; s > 0; s >>= 1) {
    if (tid < s) red[tid] += red[tid + s];
    __syncthreads();
  }
  if (tid == 0) n2[b] = red[0];
}

// ---------------------------------------------------------------------------
// K8: factors. factor1 = sum(n1)/B; factor2 = sum(n2)/B; factor3 geometric.
// ---------------------------------------------------------------------------
__global__ __launch_bounds__(256)
void finalize(const float* __restrict__ n1, const float* __restrict__ n2,
              const float* __restrict__ wc, float* __restrict__ out) {
  int tid = threadIdx.x;
  __shared__ float red[256];
  float a = 0.f;
  for (int i = tid; i < NB; i += 256) a += n1[i];
  red[tid] = a; __syncthreads();
  for (int s = 128; s > 0; s >>= 1) { if (tid < s) red[tid] += red[tid + s]; __syncthreads(); }
  if (tid == 0) out[F1_OFF] = red[0] / (float)NB;
  __syncthreads();
  a = 0.f;
  for (int i = tid; i < NB; i += 256) a += n2[i];
  red[tid] = a; __syncthreads();
  for (int s = 128; s > 0; s >>= 1) { if (tid < s) red[tid] += red[tid + s]; __syncthreads(); }
  if (tid == 0) out[F2_OFF] = red[0] / (float)NB;
  __syncthreads();

  // factor3: 32 lanes per core
  int c = tid >> 5, l = tid & 31;
  float tot = 0.f, cx = 0.f, cy = 0.f, cz = 0.f;
  for (int e = l; e < 4096; e += 32) {
    float w = fabsf(wc[c * 4096 + e]);
    int z = e & 15, y = (e >> 4) & 15, x = e >> 8;
    tot += w; cx += w * x; cy += w * y; cz += w * z;
  }
  #pragma unroll
  for (int off = 16; off > 0; off >>= 1) {
    tot += __shfl_down(tot, off);
    cx += __shfl_down(cx, off);
    cy += __shfl_down(cy, off);
    cz += __shfl_down(cz, off);
  }
  __shared__ float cent[8][3];
  if (l == 0) { cent[c][0] = cx / tot; cent[c][1] = cy / tot; cent[c][2] = cz / tot; }
  __syncthreads();
  if (tid == 0) {
    float f3 = 0.f;
    for (int i = 0; i < 8; ++i) {
      float mn = 1e30f;
      for (int j = 0; j < 8; ++j) {
        if (j == i) continue;
        float dx = cent[i][0] - cent[j][0];
        float dy = cent[i][1] - cent[j][1];
        float dz = cent[i][2] - cent[j][2];
        float d = sqrtf(dx * dx + dy * dy + dz * dz);
        mn = fminf(mn, d);
      }
      f3 += logf(mn + 1e-6f);
    }
    out[F3_OFF] = -f3 / 8.f;
  }
}

// ---------------------------------------------------------------------------
extern "C" void kernel_launch(void* const* d_in, const int* in_sizes, int n_in,
                              void* d_out, int out_size, void* d_ws, size_t ws_size,
                              hipStream_t stream) {
  const int* heads = (const int*)d_in[0];
  const int* rels = (const int*)d_in[1];
  const int* tails = (const int*)d_in[2];
  const float* ew = (const float*)d_in[3];
  const float* rw = (const float*)d_in[4];
  const float* wc = (const float*)d_in[5];
  const float* w1 = (const float*)d_in[6];
  const float* b1 = (const float*)d_in[7];
  const float* w2 = (const float*)d_in[8];
  const float* b2 = (const float*)d_in[9];
  float* out = (float*)d_out;

  uint8_t* ws = (uint8_t*)d_ws;
  const size_t EWB_SZ = (size_t)NE_PAD * DCOL * 2;   // 51,249,152
  unsigned short* ewb = (unsigned short*)ws;
  unsigned short* hrb = (unsigned short*)(ws + EWB_SZ);
  unsigned short* w1t = (unsigned short*)(ws + EWB_SZ + 2097152);
  float* hid = (float*)(ws + EWB_SZ + 2097152 + 1048576);
  unsigned short* x1b = (unsigned short*)(ws + EWB_SZ + 2097152 + 1048576 + 2097152);
  float* n1 = (float*)(ws + EWB_SZ + 2097152 + 1048576 + 2097152 + 1048576);
  float* n2 = n1 + NB;

  gather_hr<<<NB, 256, 0, stream>>>(heads, rels, tails, ew, rw, hrb, n1);
  cvt_pad<<<2048, 256, 0, stream>>>(ew, ewb, NE * DCOL / 4, NE_PAD * DCOL / 4);
  transpose_w1<<<dim3(16, 32), 256, 0, stream>>>(w1, w1t);
  gemm_nt<1><<<dim3(8, 4), 256, 0, stream>>>(hrb, w1t, hid, b1, 1024, 512, 1024, 512);
  attn_softmax<<<NB, 256, 0, stream>>>(hid, w2, b2, out + ATTN_OFF);
  triple_core<<<NB, 256, 0, stream>>>(heads, rels, tails, ew, rw, wc,
                                      out + ATTN_OFF, x1b, n2);
  gemm_nt<0><<<dim3(8, NE_PAD / 128), 256, 0, stream>>>(x1b, ewb, out, nullptr,
                                                        1024, NE_PAD, 512, NE);
  finalize<<<1, 256, 0, stream>>>(n1, n2, wc, out);
}